// Round 4
// baseline (228.721 us; speedup 1.0000x reference)
//
#include <hip/hip_runtime.h>
#include <stdint.h>

// MoleculeMultiHeadSelfAttention on MI355X (gfx950), round 4.
// B=2048, N=50, C=256, H=8, D=32.
// Key fix vs r3: lds_fence no longer carries a "memory" clobber (it serialized
// every tile's global loads behind the previous tile's LDS drain), plus explicit
// source-order prefetch of next-tile fragments. adj/mat cast is folded into
// attn via per-block LDS staging (f32 -> swizzled bf16 tiles).

typedef __attribute__((ext_vector_type(8))) short short8;
typedef __attribute__((ext_vector_type(4))) float f32x4;
typedef unsigned short u16;

#define L2E 1.4426950408889634f

__device__ __forceinline__ u16 f2bf(float f) {
  unsigned int u = __float_as_uint(f);
  u = (u + 0x7FFFu + ((u >> 16) & 1u)) >> 16;   // RNE; finite inputs
  return (u16)u;
}
__device__ __forceinline__ unsigned cvt_pk_bf16(float a, float b) {
  unsigned r;
  asm("v_cvt_pk_bf16_f32 %0, %1, %2" : "=v"(r) : "v"(a), "v"(b));
  return r;
}
__device__ __forceinline__ float exp2_fast(float x) {
#if __has_builtin(__builtin_amdgcn_exp2f)
  return __builtin_amdgcn_exp2f(x);
#else
  return __expf(x * 0.6931471805599453f);
#endif
}
// Wave-internal LDS completion point. NO "memory" clobber: global loads for
// future tiles may hoist above it. Same-lane LDS write->read order is kept by
// alias analysis; cross-lane visibility by in-order DS pipe + this waitcnt.
__device__ __forceinline__ void lds_fence() {
  asm volatile("s_waitcnt lgkmcnt(0)");
}

// ---------------- merged small casts (one tiny launch) ----------------
__global__ __launch_bounds__(256) void cast_all(
    const float* __restrict__ Wq, const float* __restrict__ Wk,
    const float* __restrict__ Wa, const float* __restrict__ Wm,
    const float* __restrict__ ba, const float* __restrict__ bm,
    u16* __restrict__ wqk, u16* __restrict__ wab, u16* __restrict__ wmb,
    float* __restrict__ bap, float* __restrict__ bmp,
    u16* __restrict__ qws, u16* __restrict__ kws) {
  const int blk = blockIdx.x, tid = threadIdx.x;
  if (blk < 64) {
    // Wq,Wk -> wqk[512][256] bf16
    int idx8 = blk * 256 + tid;
    int r = idx8 >> 5, c = (idx8 & 31) * 8;
    const float* src = (r < 256) ? (Wq + (size_t)r * 256 + c)
                                 : (Wk + (size_t)(r - 256) * 256 + c);
    float4 v0 = *(const float4*)(src);
    float4 v1 = *(const float4*)(src + 4);
    short8 o;
    o[0] = f2bf(v0.x); o[1] = f2bf(v0.y); o[2] = f2bf(v0.z); o[3] = f2bf(v0.w);
    o[4] = f2bf(v1.x); o[5] = f2bf(v1.y); o[6] = f2bf(v1.z); o[7] = f2bf(v1.w);
    *(short8*)(wqk + (size_t)idx8 * 8) = o;
  } else if (blk < 168) {
    // Wa,Wm -> [416][64] bf16 zero-padded
    int idx = (blk - 64) * 256 + tid;
    int r = idx >> 6, c = idx & 63;
    float va = 0.f, vm = 0.f;
    if (r < 400 && c < 50) { va = Wa[r * 50 + c]; vm = Wm[r * 50 + c]; }
    wab[idx] = f2bf(va); wmb[idx] = f2bf(vm);
  } else {
    // zero q/k slack rows; pad ba/bm to [8][64] f32
    short8 z = (short8){0,0,0,0,0,0,0,0};
    *(short8*)(qws + (size_t)819200 * 32 + tid * 8) = z;
    *(short8*)(kws + (size_t)819200 * 32 + tid * 8) = z;
#pragma unroll
    for (int j = 0; j < 2; ++j) {
      int idx = tid + 256 * j;          // [0,512)
      int hh = idx >> 6, m = idx & 63;
      bap[idx] = (m < 50) ? ba[hh * 50 + m] : 0.f;
      bmp[idx] = (m < 50) ? bm[hh * 50 + m] : 0.f;
    }
  }
}

// ---------------- projection GEMM (unchanged from r3) ----------------
__global__ __launch_bounds__(256) void proj_kernel(
    const float* __restrict__ x, const u16* __restrict__ wqk,
    const float* __restrict__ bq, const float* __restrict__ bk,
    u16* __restrict__ qws, u16* __restrict__ kws) {
  __shared__ char xa[64 * 512];
  __shared__ char wb[64 * 512];
  const int tid = threadIdx.x;
  const int m0 = blockIdx.x * 64;

#pragma unroll
  for (int t = 0; t < 16; ++t) {
    int idx = tid + t * 256;
    int r = idx >> 6, c4 = idx & 63;
    float4 v = *(const float4*)(x + (size_t)(m0 + r) * 256 + c4 * 4);
    unsigned long long pk = (unsigned long long)f2bf(v.x)
                          | ((unsigned long long)f2bf(v.y) << 16)
                          | ((unsigned long long)f2bf(v.z) << 32)
                          | ((unsigned long long)f2bf(v.w) << 48);
    int byte = (r * 512 + c4 * 8) ^ ((r & 7) << 4);
    *(unsigned long long*)(xa + byte) = pk;
  }
  __syncthreads();

  const int w = tid >> 6, l = tid & 63, lo = l & 15, g = l >> 4;
  short8 a[8];
  const int ra = 16 * w + lo;
#pragma unroll
  for (int ks = 0; ks < 8; ++ks)
    a[ks] = *(const short8*)(xa + ((ra * 512 + ks * 64 + g * 16) ^ ((ra & 7) << 4)));
  size_t mb[4];
#pragma unroll
  for (int i = 0; i < 4; ++i) {
    int m = m0 + 16 * w + 4 * g + i;
    int b = m / 50;
    int n = m - 50 * b;
    mb[i] = (size_t)b * 12800 + (size_t)n * 32;
  }

  for (int nt = 0; nt < 8; ++nt) {
    __syncthreads();
#pragma unroll
    for (int t = 0; t < 8; ++t) {
      int idx = tid + t * 256;
      int r = idx >> 5, c8 = idx & 31;
      short8 v = *(const short8*)(wqk + (size_t)(nt * 64 + r) * 256 + c8 * 8);
      int byte = (r * 512 + c8 * 16) ^ ((r & 7) << 4);
      *(short8*)(wb + byte) = v;
    }
    __syncthreads();

    f32x4 acc[4];
#pragma unroll
    for (int tj = 0; tj < 4; ++tj) acc[tj] = (f32x4){0.f, 0.f, 0.f, 0.f};
#pragma unroll
    for (int ks = 0; ks < 8; ++ks) {
#pragma unroll
      for (int tj = 0; tj < 4; ++tj) {
        int rb = 16 * tj + lo;
        short8 bb = *(const short8*)(wb + ((rb * 512 + ks * 64 + g * 16) ^ ((rb & 7) << 4)));
        acc[tj] = __builtin_amdgcn_mfma_f32_16x16x32_bf16(a[ks], bb, acc[tj], 0, 0, 0);
      }
    }
    const int n0 = nt * 64;
#pragma unroll
    for (int tj = 0; tj < 4; ++tj) {
      int j = n0 + 16 * tj + lo;
      int jj = j & 255;
      float bias = (j < 256) ? bq[jj] : bk[jj];
      u16* dst = (j < 256) ? qws : kws;
      int hh = jj >> 5, d = jj & 31;
#pragma unroll
      for (int i = 0; i < 4; ++i)
        dst[mb[i] + (size_t)hh * 1600 + d] = f2bf(acc[tj][i] + bias);
    }
  }
}

// ---------------- fused attention ----------------
__device__ __forceinline__ short8 ldsfrag(const u16* bLds, int row, int ks, int g) {
  return *(const short8*)((const char*)bLds +
         (((row) * 128 + ks * 64 + g * 16) ^ (((row) & 7) << 4)));
}

__device__ __forceinline__ void sm_pv_tile(
    f32x4 (&S)[4], const float (&bml)[4][4], float sl2e, float lam,
    u16* pb, const short8 (&vb)[2][2], f32x4 (&Otj)[2], int tj, int lo, int g) {
  float p[4][4];
#pragma unroll
  for (int ti = 0; ti < 4; ++ti)
#pragma unroll
    for (int i = 0; i < 4; ++i)
      p[ti][i] = exp2_fast(S[ti][i] * sl2e + bml[ti][i]);
  float t0 = (p[0][0] + p[0][1]) + (p[0][2] + p[0][3]);
  float t1 = (p[1][0] + p[1][1]) + (p[1][2] + p[1][3]);
  float t2 = (p[2][0] + p[2][1]) + (p[2][2] + p[2][3]);
  float t3 = (p[3][0] + p[3][1]) + (p[3][2] + p[3][3]);
  float sum = (t0 + t1) + (t2 + t3);
  sum += __shfl_xor(sum, 16);
  sum += __shfl_xor(sum, 32);
  float r = lam * __builtin_amdgcn_rcpf(sum);
  u16* base = pb + (tj & 1) * 1152 + lo * 72;
#pragma unroll
  for (int ti = 0; ti < 4; ++ti) {
    uint2 pk;
    pk.x = cvt_pk_bf16(p[ti][0] * r, p[ti][1] * r);
    pk.y = cvt_pk_bf16(p[ti][2] * r, p[ti][3] * r);
    *(uint2*)(base + 16 * ti + 4 * g) = pk;
  }
  lds_fence();
#pragma unroll
  for (int ks = 0; ks < 2; ++ks) {
    short8 pa = *(const short8*)(pb + (tj & 1) * 1152 + lo * 72 + ks * 32 + g * 8);
#pragma unroll
    for (int tjv = 0; tjv < 2; ++tjv)
      Otj[tjv] = __builtin_amdgcn_mfma_f32_16x16x32_bf16(pa, vb[tjv][ks], Otj[tjv], 0, 0, 0);
  }
}

// aBase: global Wa/Wm (bf16, rows of 64); bLds: LDS adj/mat tile (swizzled);
// bPad: padded f32 bias base for this head.
__device__ __forceinline__ void adj_phase(
    const u16* __restrict__ aBase, const u16* bLds, const float* __restrict__ bPad,
    float lam, u16* pb, const short8 (&vb)[2][2], f32x4 (&O)[4][2], int lo, int g) {
  short8 af[4][2];
#pragma unroll
  for (int ti = 0; ti < 4; ++ti)
#pragma unroll
    for (int ks = 0; ks < 2; ++ks)
      af[ti][ks] = *(const short8*)(aBase + (size_t)(lo + 16 * ti) * 64 + ks * 32 + g * 8);
  float bml[4][4];
#pragma unroll
  for (int ti = 0; ti < 4; ++ti) {
    f32x4 bv = *(const f32x4*)(bPad + 16 * ti + 4 * g);
#pragma unroll
    for (int i = 0; i < 4; ++i)
      bml[ti][i] = (16 * ti + 4 * g + i < 50) ? bv[i] * L2E : -1.0e30f;
  }
  short8 bc0 = ldsfrag(bLds, lo, 0, g);
  short8 bc1 = ldsfrag(bLds, lo, 1, g);
#pragma unroll
  for (int tj = 0; tj < 4; ++tj) {
    short8 bn0, bn1;
    if (tj < 3) {                       // prefetch next tile before this tile's fence
      bn0 = ldsfrag(bLds, lo + 16 * (tj + 1), 0, g);
      bn1 = ldsfrag(bLds, lo + 16 * (tj + 1), 1, g);
    }
    f32x4 S[4];
#pragma unroll
    for (int ti = 0; ti < 4; ++ti) S[ti] = (f32x4){0.f, 0.f, 0.f, 0.f};
#pragma unroll
    for (int ti = 0; ti < 4; ++ti)
      S[ti] = __builtin_amdgcn_mfma_f32_16x16x32_bf16(af[ti][0], bc0, S[ti], 0, 0, 0);
#pragma unroll
    for (int ti = 0; ti < 4; ++ti)
      S[ti] = __builtin_amdgcn_mfma_f32_16x16x32_bf16(af[ti][1], bc1, S[ti], 0, 0, 0);
    sm_pv_tile(S, bml, L2E, lam, pb, vb, O[tj], tj, lo, g);
    bc0 = bn0; bc1 = bn1;
  }
}

__global__ __launch_bounds__(256) void attn_kernel(
    const u16* __restrict__ qws, const u16* __restrict__ kws,
    const float* __restrict__ adjf, const float* __restrict__ matf,
    const u16* __restrict__ wab, const u16* __restrict__ wmb,
    const float* __restrict__ bap, const float* __restrict__ bmp,
    const float* __restrict__ lambdas, float* __restrict__ out) {
  __shared__ u16 smem[4][2304];     // per-wave: kT[32][72] then P dbuf (4608 B)
  __shared__ u16 adjm[2][4096];     // block-shared adj[b], mat[b]: [64][64] swizzled
  const int tid = threadIdx.x;
  const int w = tid >> 6, l = tid & 63, lo = l & 15, g = l >> 4;
  const int bh = blockIdx.x * 4 + w;
  const int b = bh >> 3, h = bh & 7;
  u16* sh = smem[w];

  // ---- stage adj[b], mat[b]: f32 -> bf16 [64][64], zero-padded, swizzled ----
  {
    const float* s0 = adjf + (size_t)b * 2500;
    const float* s1 = matf + (size_t)b * 2500;
#pragma unroll
    for (int mtx = 0; mtx < 2; ++mtx) {
      const float* s = mtx ? s1 : s0;
      unsigned* dstm = (unsigned*)adjm[mtx];
#pragma unroll
      for (int t = 0; t < 8; ++t) {
        int word = tid + t * 256;               // [0, 2048)
        int r = word >> 5, c2 = word & 31;      // row, u32-pair col
        unsigned val = 0;
        if (r < 50 && c2 < 25) {
          float2 v = *(const float2*)(s + r * 50 + c2 * 2);
          val = cvt_pk_bf16(v.x, v.y);
        }
        dstm[word ^ ((r & 7) << 2)] = val;
      }
    }
  }

  // softmax(lambdas[h])
  float la = lambdas[h * 3 + 0], lb = lambdas[h * 3 + 1], lc = lambdas[h * 3 + 2];
  float lmx = fmaxf(la, fmaxf(lb, lc));
  float e0 = __expf(la - lmx), e1 = __expf(lb - lmx), e2 = __expf(lc - lmx);
  float einv = 1.f / (e0 + e1 + e2);
  float lam0 = e0 * einv, lam1 = e1 * einv, lam2 = e2 * einv;

  // stage kT = V^T [32 d][72 m] in wave-private LDS, zero pad m>=50
  {
    const u16* kr = kws + (size_t)bh * 1600 + (size_t)l * 32;
#pragma unroll
    for (int ch = 0; ch < 4; ++ch) {
      short8 v = (short8){0, 0, 0, 0, 0, 0, 0, 0};
      if (l < 50) v = *(const short8*)(kr + ch * 8);
#pragma unroll
      for (int jj = 0; jj < 8; ++jj)
        sh[(ch * 8 + jj) * 72 + l] = (u16)v[jj];
    }
  }
  lds_fence();
  short8 vb[2][2];
#pragma unroll
  for (int tjv = 0; tjv < 2; ++tjv)
#pragma unroll
    for (int ks = 0; ks < 2; ++ks)
      vb[tjv][ks] = *(const short8*)(sh + (lo + 16 * tjv) * 72 + ks * 32 + g * 8);

  f32x4 O[4][2];
#pragma unroll
  for (int ti = 0; ti < 4; ++ti)
#pragma unroll
    for (int tjv = 0; tjv < 2; ++tjv) O[ti][tjv] = (f32x4){0.f, 0.f, 0.f, 0.f};

  // ---- phase 1: S^T = K·Q^T, scale (1/16)·log2e ----
  {
    short8 af[4];
#pragma unroll
    for (int ti = 0; ti < 4; ++ti)
      af[ti] = *(const short8*)(kws + (size_t)bh * 1600 + (size_t)(lo + 16 * ti) * 32 + g * 8);
    float bml[4][4];
#pragma unroll
    for (int ti = 0; ti < 4; ++ti)
#pragma unroll
      for (int i = 0; i < 4; ++i)
        bml[ti][i] = (16 * ti + 4 * g + i < 50) ? 0.f : -1.0e30f;
    const u16* qbase = qws + (size_t)bh * 1600;
    short8 qc = *(const short8*)(qbase + (size_t)lo * 32 + g * 8);
#pragma unroll
    for (int tj = 0; tj < 4; ++tj) {
      short8 qn;
      if (tj < 3)                         // prefetch next q-fragment pre-fence
        qn = *(const short8*)(qbase + (size_t)(lo + 16 * (tj + 1)) * 32 + g * 8);
      f32x4 S[4];
#pragma unroll
      for (int ti = 0; ti < 4; ++ti) S[ti] = (f32x4){0.f, 0.f, 0.f, 0.f};
#pragma unroll
      for (int ti = 0; ti < 4; ++ti)
        S[ti] = __builtin_amdgcn_mfma_f32_16x16x32_bf16(af[ti], qc, S[ti], 0, 0, 0);
      sm_pv_tile(S, bml, 0.0625f * L2E, lam0, sh, vb, O[tj], tj, lo, g);
      qc = qn;
    }
  }
  __syncthreads();   // adjm staging visible to all waves
  // ---- phases 2 & 3 ----
  adj_phase(wab + (size_t)h * 3200, adjm[0], bap + h * 64, lam1, sh, vb, O, lo, g);
  adj_phase(wmb + (size_t)h * 3200, adjm[1], bmp + h * 64, lam2, sh, vb, O, lo, g);

  // out[b][n][h*32+d], f32
  float* ob = out + ((size_t)b * 50) * 256 + h * 32;
#pragma unroll
  for (int ti = 0; ti < 4; ++ti)
#pragma unroll
    for (int i = 0; i < 4; ++i) {
      int n = 16 * ti + 4 * g + i;
      if (n < 50) {
#pragma unroll
        for (int tjv = 0; tjv < 2; ++tjv)
          ob[(size_t)n * 256 + 16 * tjv + lo] = O[ti][tjv][i];
      }
    }
}

extern "C" void kernel_launch(void* const* d_in, const int* in_sizes, int n_in,
                              void* d_out, int out_size, void* d_ws, size_t ws_size,
                              hipStream_t stream) {
  const float* x       = (const float*)d_in[0];
  const float* adj     = (const float*)d_in[1];
  const float* mat     = (const float*)d_in[2];
  const float* Wq      = (const float*)d_in[3];
  const float* bq      = (const float*)d_in[4];
  const float* Wk      = (const float*)d_in[5];
  const float* bk      = (const float*)d_in[6];
  const float* Wa      = (const float*)d_in[7];
  const float* ba      = (const float*)d_in[8];
  const float* Wm      = (const float*)d_in[9];
  const float* bm      = (const float*)d_in[10];
  const float* lambdas = (const float*)d_in[11];
  float* out = (float*)d_out;

  char* ws = (char*)d_ws;
  u16* wqk   = (u16*)ws; ws += (size_t)512 * 256 * 2;
  u16* wab   = (u16*)ws; ws += (size_t)416 * 64 * 2;
  u16* wmb   = (u16*)ws; ws += (size_t)416 * 64 * 2;
  float* bap = (float*)ws; ws += (size_t)512 * 4;
  float* bmp = (float*)ws; ws += (size_t)512 * 4;
  u16* qws   = (u16*)ws; ws += (size_t)819264 * 32 * 2;  // 16384*50 + 64 slack rows
  u16* kws   = (u16*)ws; ws += (size_t)819264 * 32 * 2;

  cast_all<<<169, 256, 0, stream>>>(Wq, Wk, Wa, Wm, ba, bm,
                                    wqk, wab, wmb, bap, bmp, qws, kws);
  proj_kernel<<<1600, 256, 0, stream>>>(x, wqk, bq, bk, qws, kws);
  attn_kernel<<<4096, 256, 0, stream>>>(qws, kws, adj, mat, wab, wmb,
                                        bap, bmp, lambdas, out);
}